// Round 21
// baseline (278.409 us; speedup 1.0000x reference)
//
#include <hip/hip_runtime.h>
#include <cstdint>

// B=4, T=4096, D=1024, H=16, d=64, C=64, N=T/C=64
#define B_ 4
#define T_ 4096
#define D_ 1024
#define H_ 16
#define HD_ 64
#define N_ 64

typedef __attribute__((ext_vector_type(8))) short s16x8;
typedef __attribute__((ext_vector_type(4))) float f32x4;

__device__ __forceinline__ unsigned short f2bf(float f) {
    unsigned int u = __builtin_bit_cast(unsigned int, f);
    u += 0x7fffu + ((u >> 16) & 1u);          // RNE
    return (unsigned short)(u >> 16);
}
__device__ __forceinline__ float bf2f(unsigned short h) {
    unsigned int u = ((unsigned int)h) << 16;
    return __builtin_bit_cast(float, u);
}
__device__ __forceinline__ void gl2lds(const short* g, short* l) {
    __builtin_amdgcn_global_load_lds(
        (const __attribute__((address_space(1))) void*)g,
        (__attribute__((address_space(3))) void*)l, 16, 0, 0);
}
#define MFMA16(a, b, c) __builtin_amdgcn_mfma_f32_16x16x32_bf16(a, b, c, 0, 0, 0)
#define SB0() __builtin_amdgcn_sched_barrier(0)
#define BAR() __builtin_amdgcn_s_barrier()

#define BF_P1 ((short)0x3F80)
#define BF_M1 ((short)0xBF80)

// ---------------------------------------------------------------------------
// Combined converter: fp32 -> bf16 for X, Wqkv, Wo in ONE launch.
// ---------------------------------------------------------------------------
__global__ __launch_bounds__(256)
void k_cvt3(const float* __restrict__ inX,  short* __restrict__ outX,  int nX,
            const float* __restrict__ inW,  short* __restrict__ outW,  int nW,
            const float* __restrict__ inO,  short* __restrict__ outO,  int nO)
{
    const int ntot = nX + nW + nO;
    int i = blockIdx.x * blockDim.x + threadIdx.x;
    const int stride = gridDim.x * blockDim.x;
    for (; i < ntot; i += stride) {
        const float* src;
        short* dst;
        int j = i;
        if (j < nX)            { src = inX; dst = outX; }
        else if (j < nX + nW)  { j -= nX; src = inW; dst = outW; }
        else                   { j -= nX + nW; src = inO; dst = outO; }
        float4 f = ((const float4*)src)[j];
        short4 o;
        o.x = (short)f2bf(f.x); o.y = (short)f2bf(f.y);
        o.z = (short)f2bf(f.z); o.w = (short)f2bf(f.w);
        *(short4*)(dst + j * 4) = o;
    }
}

// ---------------------------------------------------------------------------
// k_gemm6: m97-recipe GEMM for the fused QKV step. O = A @ B^T.
// 128x128 tile, BK=32, 256 thr (4 waves 2x2, per-wave 64x64, acc 64 VGPR),
// DOUBLE-buffered 32 KB LDS (up to 4 blocks/CU); per tile:
// stage(t+1) 4 gl2lds -> vmcnt(4) -> BAR -> 8 ds_read_b128 + 16 MFMA -> BAR.
// 64B LDS rows; swizzle (r18-verified, 0 conflicts): phys 16B slot =
// (q + (R>>1)) & 3; gl2lds source slot = ((l&3) - ((l>>3)&3)) & 3.
// MODE 0: fused qkv epilogue by col0>>10 (Qb bf16*0.125 / Kb8 / VbT8).
// ---------------------------------------------------------------------------
template<int MODE, int KD, int NCB>
__global__ __launch_bounds__(256, 4)
void k_gemm6(const short* __restrict__ A, const short* __restrict__ Bm,
             short* __restrict__ Oq, signed char* __restrict__ K8,
             signed char* __restrict__ V8, float* __restrict__ Yf)
{
    __shared__ __align__(16) short LS[2][2][4096];  // [dbuf][A/B][128 rows x 32]

    const int tid = threadIdx.x;
    const int nwg = 128 * NCB;
    const int bid = blockIdx.x;
    const int sz  = (bid & 7) * (nwg >> 3) + (bid >> 3);   // XCD-contiguous
    const int cb  = sz % NCB, rb = sz / NCB;
    const int row0 = rb * 128, col0 = cb * 128;

    const int lane = tid & 63, w = tid >> 6;        // 4 waves, 2x2
    const int wr = w >> 1, wc = w & 1;
    const int cl = lane & 15, rg = lane >> 4;       // rg = 16B K-slot 0..3

    // staging: lane l -> row (l>>2) of a 16-row group, phys slot (l&3);
    // source slot inverts the read swizzle (verified 0 conflicts in r18).
    const int sr  = lane >> 2;                            // 0..15
    const int ssl = ((lane & 3) - ((lane >> 3) & 3)) & 3; // 0..3
    const short* gA = A  + (size_t)(row0 + w * 32 + sr) * KD + ssl * 8;
    const short* gB = Bm + (size_t)(col0 + w * 32 + sr) * KD + ssl * 8;

    f32x4 acc[4][4];
    #pragma unroll
    for (int i = 0; i < 4; ++i)
        #pragma unroll
        for (int j = 0; j < 4; ++j) acc[i][j] = (f32x4)0.f;

    // stage tile t into buf pb: 2 gl2lds per matrix per wave (16 rows each)
    auto stage = [&](int pb, int t) {
        const int ko = t * 32;
        gl2lds(gA + ko,                   &LS[pb][0][(w * 32     ) * 32]);
        gl2lds(gA + ko + (size_t)16 * KD, &LS[pb][0][(w * 32 + 16) * 32]);
        gl2lds(gB + ko,                   &LS[pb][1][(w * 32     ) * 32]);
        gl2lds(gB + ko + (size_t)16 * KD, &LS[pb][1][(w * 32 + 16) * 32]);
    };
    // swizzled read: row R, logical 16B slot q (0..3)
    auto ldf = [&](const short* base, int R, int q) -> s16x8 {
        const int off = R * 64 + (((q + (R >> 1)) & 3) << 4);
        return *(const s16x8*)((const char*)base + off);
    };

    const int nt = KD / 32;
    stage(0, 0);
    for (int t = 0; t < nt; ++t) {
        const int pb = t & 1;
        if (t + 1 < nt) {
            stage(pb ^ 1, t + 1);
            asm volatile("s_waitcnt vmcnt(4)" ::: "memory");
        } else {
            asm volatile("s_waitcnt vmcnt(0)" ::: "memory");
        }
        BAR();
        SB0();
        const short* bA = &LS[pb][0][0];
        const short* bB = &LS[pb][1][0];
        s16x8 fb[4];
        #pragma unroll
        for (int ni = 0; ni < 4; ++ni)
            fb[ni] = ldf(bB, wc * 64 + ni * 16 + cl, rg);
        #pragma unroll
        for (int mi = 0; mi < 4; ++mi) {
            s16x8 fa = ldf(bA, wr * 64 + mi * 16 + cl, rg);
            __builtin_amdgcn_s_setprio(1);
            #pragma unroll
            for (int ni = 0; ni < 4; ++ni)
                acc[mi][ni] = MFMA16(fa, fb[ni], acc[mi][ni]);
            __builtin_amdgcn_s_setprio(0);
        }
        SB0();
        BAR();
    }

    const int m0 = row0 + wr * 64, n0 = col0 + wc * 64;
    if (MODE == 0) {
        const int s = col0 >> 10;             // 0:q 1:k 2:v, uniform per block
        #pragma unroll
        for (int ni = 0; ni < 4; ++ni) {
            const int col = n0 + ni * 16 + cl;
            const int h = (col & 1023) >> 6, dd = col & 63;
            #pragma unroll
            for (int mi = 0; mi < 4; ++mi)
                #pragma unroll
                for (int r = 0; r < 4; ++r) {
                    const int bt = m0 + mi * 16 + rg * 4 + r;
                    const int bb = bt >> 12, t = bt & (T_ - 1);
                    const size_t bh64 = (size_t)(bb * H_ + h);
                    const float v = acc[mi][ni][r];
                    if (s == 0) {
                        Oq[(bh64 * T_ + t) * 64 + dd] =
                            (short)f2bf(v * 0.125f);          // Qb [c][d]
                    } else if (s == 1) {
                        K8[(bh64 * T_ + t) * 64 + dd] =
                            (v >= 0.f) ? 1 : -1;              // Kb8 [c][d]
                    } else {
                        const size_t otr = bh64 * ((size_t)T_ * 64)
                                         + (size_t)(t >> 6) * 4096 + dd * 64 + (t & 63);
                        V8[otr] = (v >= 0.f) ? 1 : -1;        // VbT8 [d][c]
                    }
                }
        }
    } else {
        #pragma unroll
        for (int ni = 0; ni < 4; ++ni) {
            const int col = n0 + ni * 16 + cl;
            #pragma unroll
            for (int mi = 0; mi < 4; ++mi)
                #pragma unroll
                for (int r = 0; r < 4; ++r)
                    Yf[(size_t)(m0 + mi * 16 + rg * 4 + r) * D_ + col] =
                        acc[mi][ni][r];
        }
    }
}

// ---------------------------------------------------------------------------
// k_gemm2 (frozen session best): 256x128 tile, BK=64, 512 thr, 48 KiB LDS.
// MODE 1: fp32 Y (out GEMM only in this build).
// ---------------------------------------------------------------------------
template<int MODE, int KD, int NCB>
__global__ __launch_bounds__(512, 4)
void k_gemm2(const short* __restrict__ A, const short* __restrict__ Bm,
             short* __restrict__ Oq, signed char* __restrict__ K8,
             signed char* __restrict__ V8, float* __restrict__ Yf)
{
    __shared__ __align__(16) short LA[256 * 64];   // 32 KiB
    __shared__ __align__(16) short LB[128 * 64];   // 16 KiB

    const int tid = threadIdx.x;
    const int nwg = 64 * NCB;
    const int bid = blockIdx.x;
    const int sz  = (bid & 7) * (nwg >> 3) + (bid >> 3);   // XCD-contiguous
    const int cb  = sz % NCB, rb = sz / NCB;
    const int row0 = rb * 256, col0 = cb * 128;

    const int lane = tid & 63, w = tid >> 6;
    const int wr = w >> 1, wc = w & 1;
    const int cl = lane & 15, rg = lane >> 4;

    const int sr8 = lane >> 3;
    const int slg = ((lane & 7) ^ sr8) * 8;
    const short* gA = A  + (size_t)(row0 + w * 32 + sr8) * KD + slg;
    const short* gB = Bm + (size_t)(col0 + w * 16 + sr8) * KD + slg;

    f32x4 acc[4][4];
    #pragma unroll
    for (int i = 0; i < 4; ++i)
        #pragma unroll
        for (int j = 0; j < 4; ++j) acc[i][j] = (f32x4)0.f;

    auto stage = [&](int t) {
        const int ko = t * 64;
        #pragma unroll
        for (int c = 0; c < 4; ++c)
            gl2lds(gA + ko + (size_t)c * 8 * KD, &LA[(w * 32 + c * 8) * 64]);
        #pragma unroll
        for (int c = 0; c < 2; ++c)
            gl2lds(gB + ko + (size_t)c * 8 * KD, &LB[(w * 16 + c * 8) * 64]);
    };
    auto ldf = [&](const short* base, int R, int q) -> s16x8 {
        return *(const s16x8*)((const char*)base + R * 128 + ((q ^ (R & 7)) << 4));
    };

    const int nt = KD / 64;
    stage(0);
    for (int t = 0; t < nt; ++t) {
        asm volatile("s_waitcnt vmcnt(0)" ::: "memory");
        BAR();
        SB0();
        #pragma unroll
        for (int kk = 0; kk < 2; ++kk) {
            s16x8 fb[4];
            #pragma unroll
            for (int ni = 0; ni < 4; ++ni)
                fb[ni] = ldf(LB, wc * 64 + ni * 16 + cl, kk * 4 + rg);
            #pragma unroll
            for (int mi = 0; mi < 4; ++mi) {
                s16x8 fa = ldf(LA, wr * 64 + mi * 16 + cl, kk * 4 + rg);
                __builtin_amdgcn_s_setprio(1);
                #pragma unroll
                for (int ni = 0; ni < 4; ++ni)
                    acc[mi][ni] = MFMA16(fa, fb[ni], acc[mi][ni]);
                __builtin_amdgcn_s_setprio(0);
            }
        }
        SB0();
        BAR();
        if (t + 1 < nt) stage(t + 1);
    }

    const int m0 = row0 + wr * 64, n0 = col0 + wc * 64;
    if (MODE == 1) {
        #pragma unroll
        for (int ni = 0; ni < 4; ++ni) {
            const int col = n0 + ni * 16 + cl;
            #pragma unroll
            for (int mi = 0; mi < 4; ++mi)
                #pragma unroll
                for (int r = 0; r < 4; ++r)
                    Yf[(size_t)(m0 + mi * 16 + rg * 4 + r) * D_ + col] =
                        acc[mi][ni][r];
        }
    }
}

// ---------------------------------------------------------------------------
// K2a (MFMA): per chunk, ckvT[dd][kd] = sum_c v[c][dd] k[c][kd] -> CKV8 int8.
// ---------------------------------------------------------------------------
__global__ __launch_bounds__(256)
void k_chunkA(const signed char* __restrict__ Kb8,
              const signed char* __restrict__ VbT8,
              signed char* __restrict__ CKV8)
{
    __shared__ __align__(16) short KTs[4096], VTs[4096];
    __shared__ __align__(16) signed char Cs8[4096];
    const int tid = threadIdx.x;
    const int bh = blockIdx.x >> 6, n = blockIdx.x & 63;
    const size_t kbase = ((size_t)bh * T_ + n * 64) * 64;          // [c][dd]
    const size_t vbase = (size_t)bh * T_ * 64 + (size_t)n * 4096;  // [dd][c]

    {
        const int off = tid * 16;
        int4 vr = *(const int4*)(VbT8 + vbase + off);
        const signed char* vb = (const signed char*)&vr;
        const int vrow = off >> 6, vcb = off & 63;
        #pragma unroll
        for (int jj = 0; jj < 2; ++jj) {
            s16x8 v;
            #pragma unroll
            for (int j = 0; j < 8; ++j)
                v[j] = (vb[jj*8+j] >= 0) ? BF_P1 : BF_M1;
            const int o = (vrow * 128 + (vcb + jj * 8) * 2) ^ ((vrow & 7) << 4);
            *(s16x8*)((char*)VTs + o) = v;
        }
        int4 kr = *(const int4*)(Kb8 + kbase + off);
        const signed char* kb = (const signed char*)&kr;
        const int c = off >> 6, d0 = off & 63;
        #pragma unroll
        for (int j = 0; j < 16; ++j) {
            const int dd = d0 + j;
            const short sv = (kb[j] >= 0) ? BF_P1 : BF_M1;
            const int o2 = (dd * 128 + c * 2) ^ ((dd & 7) << 4);
            *(short*)((char*)KTs + o2) = sv;
        }
    }
    __syncthreads();

    const int lane = tid & 63, w = tid >> 6;
    const int cl = lane & 15, rg = lane >> 4;
    auto frag = [&](const short* l, int rowbase, int kk) -> s16x8 {
        const int row = rowbase + cl;
        int off = row * 128 + kk * 64 + rg * 16;
        off ^= (row & 7) << 4;
        return *(const s16x8*)((const char*)l + off);
    };

    f32x4 a3[4];
    #pragma unroll
    for (int ni = 0; ni < 4; ++ni) a3[ni] = (f32x4)0.f;
    const s16x8 va0 = frag(VTs, w * 16, 0), va1 = frag(VTs, w * 16, 1);
    #pragma unroll
    for (int ni = 0; ni < 4; ++ni) {
        a3[ni] = MFMA16(va0, frag(KTs, ni * 16, 0), a3[ni]);
        a3[ni] = MFMA16(va1, frag(KTs, ni * 16, 1), a3[ni]);
    }
    #pragma unroll
    for (int ni = 0; ni < 4; ++ni)
        #pragma unroll
        for (int r = 0; r < 4; ++r) {
            const int m = w * 16 + rg * 4 + r;     // dd
            const int c = ni * 16 + cl;            // kd
            Cs8[m * 64 + c] = (signed char)(int)a3[ni][r];
        }
    __syncthreads();
    const size_t c8 = ((size_t)bh * 64 + n) * 4096;
    *(int4*)(CKV8 + c8 + tid * 16) = *(const int4*)(Cs8 + tid * 16);
}

// ---------------------------------------------------------------------------
// K3: integer exclusive scan of CKV8 over chunks -> PB bf16; FM fp32 exact.
// ---------------------------------------------------------------------------
__global__ __launch_bounds__(256)
void k_scan2(const signed char* __restrict__ CKV8, short* __restrict__ PB,
             float* __restrict__ FM, float* __restrict__ FC)
{
    const int bh = blockIdx.x >> 4;
    const int e  = (blockIdx.x & 15) * 256 + threadIdx.x;   // dd*64+kd
    const size_t b8 = (size_t)bh * N_ * 4096 + e;
    const size_t bp = (size_t)bh * N_ * 4096 + e;
    int run = 0;
    #pragma unroll
    for (int nn = 0; nn < 64; ++nn) {
        PB[bp + (size_t)nn * 4096] = (short)f2bf((float)run);
        run += (int)CKV8[b8 + (size_t)nn * 4096];
    }
    FM[(size_t)bh * 4096 + (e & 63) * 64 + (e >> 6)] = (float)run;
    if ((blockIdx.x & 15) == 0 && threadIdx.x == 0) FC[bh] = (float)T_;
}

// ---------------------------------------------------------------------------
// K4 (MFMA, fused): S = mask(Q K^T); intra = S V; cross = Q @ P;
// OMb = bf16((intra + cross) / total).
// ---------------------------------------------------------------------------
__global__ __launch_bounds__(256)
void k_cross3(const short* __restrict__ Qb, const signed char* __restrict__ Kb8,
              const signed char* __restrict__ VbT8, const short* __restrict__ PB,
              short* __restrict__ OMb)
{
    __shared__ __align__(16) short Qs[4096], Ks[4096], VTs[4096], Ps[4096], Ss[4096];
    const int tid = threadIdx.x;
    const int bh = blockIdx.x >> 6, n = blockIdx.x & 63;
    const size_t cbase = ((size_t)bh * T_ + n * 64) * 64;
    const size_t kbase = cbase;                                    // [c][dd]
    const size_t vbase = (size_t)bh * T_ * 64 + (size_t)n * 4096;  // [dd][c]

    auto stage_tile = [&](const short* g, short* l) {
        #pragma unroll
        for (int p = 0; p < 2; ++p) {
            const int off = tid * 16 + p * 4096;
            const int r = off >> 7;
            s16x8 v = *(const s16x8*)(g + (off >> 1));
            *(s16x8*)((char*)l + (off ^ ((r & 7) << 4))) = v;
        }
    };
    stage_tile(Qb + cbase, Qs);
    stage_tile(PB + ((size_t)bh * 64 + n) * 4096, Ps);
    {
        const int off = tid * 16;
        int4 kr = *(const int4*)(Kb8 + kbase + off);
        const signed char* kb = (const signed char*)&kr;
        int4 vr = *(const int4*)(VbT8 + vbase + off);
        const signed char* vb = (const signed char*)&vr;
        const int row = off >> 6, cb = off & 63;
        #pragma unroll
        for (int jj = 0; jj < 2; ++jj) {
            s16x8 kv, vv;
            #pragma unroll
            for (int j = 0; j < 8; ++j) {
                kv[j] = (kb[jj*8+j] >= 0) ? BF_P1 : BF_M1;
                vv[j] = (vb[jj*8+j] >= 0) ? BF_P1 : BF_M1;
            }
            const int o = (row * 128 + (cb + jj * 8) * 2) ^ ((row & 7) << 4);
            *(s16x8*)((char*)Ks  + o) = kv;
            *(s16x8*)((char*)VTs + o) = vv;
        }
    }
    __syncthreads();

    const int lane = tid & 63, w = tid >> 6;
    const int cl = lane & 15, rg = lane >> 4;
    auto frag = [&](const short* l, int rowbase, int kk) -> s16x8 {
        const int row = rowbase + cl;
        int off = row * 128 + kk * 64 + rg * 16;
        off ^= (row & 7) << 4;
        return *(const s16x8*)((const char*)l + off);
    };

    const s16x8 qa0 = frag(Qs, w * 16, 0), qa1 = frag(Qs, w * 16, 1);
    {
        f32x4 a1[4];
        #pragma unroll
        for (int ni = 0; ni < 4; ++ni) a1[ni] = (f32x4)0.f;
        #pragma unroll
        for (int ni = 0; ni < 4; ++ni) {
            a1[ni] = MFMA16(qa0, frag(Ks, ni * 16, 0), a1[ni]);
            a1[ni] = MFMA16(qa1, frag(Ks, ni * 16, 1), a1[ni]);
        }
        #pragma unroll
        for (int ni = 0; ni < 4; ++ni)
            #pragma unroll
            for (int r = 0; r < 4; ++r) {
                const int i = w * 16 + rg * 4 + r, j = ni * 16 + cl;
                const float v = (j <= i) ? a1[ni][r] : 0.f;
                const int off = (i * 128 + j * 2) ^ ((i & 7) << 4);
                *(short*)((char*)Ss + off) = (short)f2bf(v);
            }
    }
    __syncthreads();

    {
        f32x4 a2[4], a3[4];
        #pragma unroll
        for (int ni = 0; ni < 4; ++ni) { a2[ni] = (f32x4)0.f; a3[ni] = (f32x4)0.f; }
        const s16x8 sa0 = frag(Ss, w * 16, 0), sa1 = frag(Ss, w * 16, 1);
        #pragma unroll
        for (int ni = 0; ni < 4; ++ni) {
            a2[ni] = MFMA16(sa0, frag(VTs, ni * 16, 0), a2[ni]);
            a2[ni] = MFMA16(sa1, frag(VTs, ni * 16, 1), a2[ni]);
            a3[ni] = MFMA16(qa0, frag(Ps, ni * 16, 0), a3[ni]);
            a3[ni] = MFMA16(qa1, frag(Ps, ni * 16, 1), a3[ni]);
        }
        #pragma unroll
        for (int ni = 0; ni < 4; ++ni)
            #pragma unroll
            for (int r = 0; r < 4; ++r) {
                const int i = w * 16 + rg * 4 + r, j = ni * 16 + cl;
                const float invt = 1.0f / (float)(n * 64 + i + 1);
                const float f = (a2[ni][r] + a3[ni][r]) * invt;
                const int off = (i * 128 + j * 2) ^ ((i & 7) << 4);
                *(short*)((char*)Qs + off) = (short)f2bf(f);
            }
    }
    __syncthreads();

    const int bb = bh >> 4, h = bh & 15;
    #pragma unroll
    for (int p = 0; p < 2; ++p) {
        const int off = tid * 16 + p * 4096;
        const int r = off >> 7;
        const int lo = off ^ ((r & 7) << 4);
        s16x8 v = *(const s16x8*)((char*)Qs + lo);
        const size_t gi = ((size_t)bb * T_ + n * 64 + r) * D_
                        + h * 64 + ((off & 127) >> 1);
        *(s16x8*)(OMb + gi) = v;
    }
}

extern "C" void kernel_launch(void* const* d_in, const int* in_sizes, int n_in,
                              void* d_out, int out_size, void* d_ws, size_t ws_size,
                              hipStream_t stream)
{
    const float* X    = (const float*)d_in[0];
    const float* Wqkv = (const float*)d_in[1];
    const float* Wo   = (const float*)d_in[2];

    float* Y  = (float*)d_out;                       // [B,T,D]
    float* FM = Y + (size_t)B_ * T_ * D_;            // [B,H,64,64]
    float* FC = FM + (size_t)B_ * H_ * HD_ * HD_;    // [B,H,1,1]

    char* ws = (char*)d_ws;
    const size_t Mi = 1048576;
    short*       Qb     = (short*)(ws + 0 * Mi);         // 32 MiB
    signed char* Kb8    = (signed char*)(ws + 32 * Mi);  // 16 MiB
    signed char* VbT8   = (signed char*)(ws + 48 * Mi);  // 16 MiB
    short*       PB     = (short*)(ws + 64 * Mi);        // 32 MiB
    short*       Xb     = (short*)(ws + 96 * Mi);        // 32 MiB (early)
    short*       OMb    = (short*)(ws + 96 * Mi);        // 32 MiB (late)
    signed char* CKV8   = (signed char*)(ws + 128 * Mi); // 16 MiB
    short*       Wqkvb  = (short*)(ws + 144 * Mi);       //  6 MiB
    short*       WoS    = (short*)(ws + 150 * Mi);       //  2 MiB
    if (ws_size < (size_t)152 * Mi) return;

    dim3 blk(256), blkg(512);
    k_cvt3<<<dim3(2048), blk, 0, stream>>>(X, Xb, 4194304,
                                           Wqkv, Wqkvb, 786432,
                                           Wo, WoS, 262144);
    // fused QKV GEMM (m97 recipe): M=16384, N=3072 -> 128x24 = 3072 blocks
    k_gemm6<0, 1024, 24><<<dim3(3072), blk, 0, stream>>>(Xb, Wqkvb, Qb, Kb8, VbT8, nullptr);
    k_chunkA<<<dim3(4096), blk, 0, stream>>>(Kb8, VbT8, CKV8);
    k_scan2 <<<dim3(1024), blk, 0, stream>>>(CKV8, PB, FM, FC);
    k_cross3<<<dim3(4096), blk, 0, stream>>>(Qb, Kb8, VbT8, PB, OMb);
    // out GEMM (frozen): M=16384, N=1024 -> NCB=8, grid 512
    k_gemm2<1, 1024, 8><<<dim3(512), blkg, 0, stream>>>(OMb, WoS, nullptr, nullptr, nullptr, Y);
}

// Round 22
// 256.560 us; speedup vs baseline: 1.0852x; 1.0852x over previous
//
#include <hip/hip_runtime.h>
#include <cstdint>

// B=4, T=4096, D=1024, H=16, d=64, C=64, N=T/C=64
#define B_ 4
#define T_ 4096
#define D_ 1024
#define H_ 16
#define HD_ 64
#define N_ 64

typedef __attribute__((ext_vector_type(8))) short s16x8;
typedef __attribute__((ext_vector_type(4))) float f32x4;

__device__ __forceinline__ unsigned short f2bf(float f) {
    unsigned int u = __builtin_bit_cast(unsigned int, f);
    u += 0x7fffu + ((u >> 16) & 1u);          // RNE
    return (unsigned short)(u >> 16);
}
__device__ __forceinline__ float bf2f(unsigned short h) {
    unsigned int u = ((unsigned int)h) << 16;
    return __builtin_bit_cast(float, u);
}
__device__ __forceinline__ void gl2lds(const short* g, short* l) {
    __builtin_amdgcn_global_load_lds(
        (const __attribute__((address_space(1))) void*)g,
        (__attribute__((address_space(3))) void*)l, 16, 0, 0);
}
#define MFMA16(a, b, c) __builtin_amdgcn_mfma_f32_16x16x32_bf16(a, b, c, 0, 0, 0)
#define SB0() __builtin_amdgcn_sched_barrier(0)
#define BAR() __builtin_amdgcn_s_barrier()

#define BF_P1 ((short)0x3F80)
#define BF_M1 ((short)0xBF80)

// ---------------------------------------------------------------------------
// Combined converter: fp32 -> bf16 for X, Wqkv, Wo in ONE launch (ranges
// partitioned by flat float4 index; Wo conversion is dependency-free and
// its buffer is untouched until the out-GEMM).
// ---------------------------------------------------------------------------
__global__ __launch_bounds__(256)
void k_cvt3(const float* __restrict__ inX,  short* __restrict__ outX,  int nX,
            const float* __restrict__ inW,  short* __restrict__ outW,  int nW,
            const float* __restrict__ inO,  short* __restrict__ outO,  int nO)
{
    const int ntot = nX + nW + nO;
    int i = blockIdx.x * blockDim.x + threadIdx.x;
    const int stride = gridDim.x * blockDim.x;
    for (; i < ntot; i += stride) {
        const float* src;
        short* dst;
        int j = i;
        if (j < nX)            { src = inX; dst = outX; }
        else if (j < nX + nW)  { j -= nX; src = inW; dst = outW; }
        else                   { j -= nX + nW; src = inO; dst = outO; }
        float4 f = ((const float4*)src)[j];
        short4 o;
        o.x = (short)f2bf(f.x); o.y = (short)f2bf(f.y);
        o.z = (short)f2bf(f.z); o.w = (short)f2bf(f.w);
        *(short4*)(dst + j * 4) = o;
    }
}

// ---------------------------------------------------------------------------
// bf16 MFMA GEMM, TLP structure (r12/r13 core, frozen session best):
// O = A @ B^T. 256x128 tile, BK=64, 512 thr (8 waves 4x2, per-wave 64x64,
// acc 64 VGPR), single-buffered 48 KiB LDS, launch_bounds(512,4).
// Swizzle: 128B rows, phys 16B slot = logical ^ (row&7), pre-swizzled src.
// MODE 0: fused qkv epilogue by col0>>10: s=0 -> Qb bf16*0.125,
//         s=1 -> Kb8 int8 sign [c][d], s=2 -> VbT8 int8 sign [d][c].
// MODE 1: fp32 Y.
// ---------------------------------------------------------------------------
template<int MODE, int KD, int NCB>
__global__ __launch_bounds__(512, 4)
void k_gemm2(const short* __restrict__ A, const short* __restrict__ Bm,
             short* __restrict__ Oq, signed char* __restrict__ K8,
             signed char* __restrict__ V8, float* __restrict__ Yf)
{
    __shared__ __align__(16) short LA[256 * 64];   // 32 KiB
    __shared__ __align__(16) short LB[128 * 64];   // 16 KiB

    const int tid = threadIdx.x;
    const int nwg = 64 * NCB;
    const int bid = blockIdx.x;
    const int sz  = (bid & 7) * (nwg >> 3) + (bid >> 3);   // XCD-contiguous
    const int cb  = sz % NCB, rb = sz / NCB;
    const int row0 = rb * 256, col0 = cb * 128;

    const int lane = tid & 63, w = tid >> 6;
    const int wr = w >> 1, wc = w & 1;
    const int cl = lane & 15, rg = lane >> 4;

    const int sr8 = lane >> 3;
    const int slg = ((lane & 7) ^ sr8) * 8;
    const short* gA = A  + (size_t)(row0 + w * 32 + sr8) * KD + slg;
    const short* gB = Bm + (size_t)(col0 + w * 16 + sr8) * KD + slg;

    f32x4 acc[4][4];
    #pragma unroll
    for (int i = 0; i < 4; ++i)
        #pragma unroll
        for (int j = 0; j < 4; ++j) acc[i][j] = (f32x4)0.f;

    auto stage = [&](int t) {
        const int ko = t * 64;
        #pragma unroll
        for (int c = 0; c < 4; ++c)
            gl2lds(gA + ko + (size_t)c * 8 * KD, &LA[(w * 32 + c * 8) * 64]);
        #pragma unroll
        for (int c = 0; c < 2; ++c)
            gl2lds(gB + ko + (size_t)c * 8 * KD, &LB[(w * 16 + c * 8) * 64]);
    };
    auto ldf = [&](const short* base, int R, int q) -> s16x8 {
        return *(const s16x8*)((const char*)base + R * 128 + ((q ^ (R & 7)) << 4));
    };

    const int nt = KD / 64;
    stage(0);
    for (int t = 0; t < nt; ++t) {
        asm volatile("s_waitcnt vmcnt(0)" ::: "memory");
        BAR();
        SB0();
        #pragma unroll
        for (int kk = 0; kk < 2; ++kk) {
            s16x8 fb[4];
            #pragma unroll
            for (int ni = 0; ni < 4; ++ni)
                fb[ni] = ldf(LB, wc * 64 + ni * 16 + cl, kk * 4 + rg);
            #pragma unroll
            for (int mi = 0; mi < 4; ++mi) {
                s16x8 fa = ldf(LA, wr * 64 + mi * 16 + cl, kk * 4 + rg);
                __builtin_amdgcn_s_setprio(1);
                #pragma unroll
                for (int ni = 0; ni < 4; ++ni)
                    acc[mi][ni] = MFMA16(fa, fb[ni], acc[mi][ni]);
                __builtin_amdgcn_s_setprio(0);
            }
        }
        SB0();
        BAR();
        if (t + 1 < nt) stage(t + 1);
    }

    const int m0 = row0 + wr * 64, n0 = col0 + wc * 64;
    if (MODE == 0) {
        const int s = col0 >> 10;             // 0:q 1:k 2:v, uniform per block
        #pragma unroll
        for (int ni = 0; ni < 4; ++ni) {
            const int col = n0 + ni * 16 + cl;
            const int h = (col & 1023) >> 6, dd = col & 63;
            #pragma unroll
            for (int mi = 0; mi < 4; ++mi)
                #pragma unroll
                for (int r = 0; r < 4; ++r) {
                    const int bt = m0 + mi * 16 + rg * 4 + r;
                    const int bb = bt >> 12, t = bt & (T_ - 1);
                    const size_t bh64 = (size_t)(bb * H_ + h);
                    const float v = acc[mi][ni][r];
                    if (s == 0) {
                        Oq[(bh64 * T_ + t) * 64 + dd] =
                            (short)f2bf(v * 0.125f);          // Qb [c][d]
                    } else if (s == 1) {
                        K8[(bh64 * T_ + t) * 64 + dd] =
                            (v >= 0.f) ? 1 : -1;              // Kb8 [c][d]
                    } else {
                        const size_t otr = bh64 * ((size_t)T_ * 64)
                                         + (size_t)(t >> 6) * 4096 + dd * 64 + (t & 63);
                        V8[otr] = (v >= 0.f) ? 1 : -1;        // VbT8 [d][c]
                    }
                }
        }
    } else {
        #pragma unroll
        for (int ni = 0; ni < 4; ++ni) {
            const int col = n0 + ni * 16 + cl;
            #pragma unroll
            for (int mi = 0; mi < 4; ++mi)
                #pragma unroll
                for (int r = 0; r < 4; ++r)
                    Yf[(size_t)(m0 + mi * 16 + rg * 4 + r) * D_ + col] =
                        acc[mi][ni][r];
        }
    }
}

// ---------------------------------------------------------------------------
// K2a (MFMA): per chunk, ckvT[dd][kd] = sum_c v[c][dd] k[c][kd] -> CKV8 int8.
// ---------------------------------------------------------------------------
__global__ __launch_bounds__(256)
void k_chunkA(const signed char* __restrict__ Kb8,
              const signed char* __restrict__ VbT8,
              signed char* __restrict__ CKV8)
{
    __shared__ __align__(16) short KTs[4096], VTs[4096];
    __shared__ __align__(16) signed char Cs8[4096];
    const int tid = threadIdx.x;
    const int bh = blockIdx.x >> 6, n = blockIdx.x & 63;
    const size_t kbase = ((size_t)bh * T_ + n * 64) * 64;          // [c][dd]
    const size_t vbase = (size_t)bh * T_ * 64 + (size_t)n * 4096;  // [dd][c]

    {
        const int off = tid * 16;
        int4 vr = *(const int4*)(VbT8 + vbase + off);
        const signed char* vb = (const signed char*)&vr;
        const int vrow = off >> 6, vcb = off & 63;
        #pragma unroll
        for (int jj = 0; jj < 2; ++jj) {
            s16x8 v;
            #pragma unroll
            for (int j = 0; j < 8; ++j)
                v[j] = (vb[jj*8+j] >= 0) ? BF_P1 : BF_M1;
            const int o = (vrow * 128 + (vcb + jj * 8) * 2) ^ ((vrow & 7) << 4);
            *(s16x8*)((char*)VTs + o) = v;
        }
        int4 kr = *(const int4*)(Kb8 + kbase + off);
        const signed char* kb = (const signed char*)&kr;
        const int c = off >> 6, d0 = off & 63;
        #pragma unroll
        for (int j = 0; j < 16; ++j) {
            const int dd = d0 + j;
            const short sv = (kb[j] >= 0) ? BF_P1 : BF_M1;
            const int o2 = (dd * 128 + c * 2) ^ ((dd & 7) << 4);
            *(short*)((char*)KTs + o2) = sv;
        }
    }
    __syncthreads();

    const int lane = tid & 63, w = tid >> 6;
    const int cl = lane & 15, rg = lane >> 4;
    auto frag = [&](const short* l, int rowbase, int kk) -> s16x8 {
        const int row = rowbase + cl;
        int off = row * 128 + kk * 64 + rg * 16;
        off ^= (row & 7) << 4;
        return *(const s16x8*)((const char*)l + off);
    };

    f32x4 a3[4];
    #pragma unroll
    for (int ni = 0; ni < 4; ++ni) a3[ni] = (f32x4)0.f;
    const s16x8 va0 = frag(VTs, w * 16, 0), va1 = frag(VTs, w * 16, 1);
    #pragma unroll
    for (int ni = 0; ni < 4; ++ni) {
        a3[ni] = MFMA16(va0, frag(KTs, ni * 16, 0), a3[ni]);
        a3[ni] = MFMA16(va1, frag(KTs, ni * 16, 1), a3[ni]);
    }
    #pragma unroll
    for (int ni = 0; ni < 4; ++ni)
        #pragma unroll
        for (int r = 0; r < 4; ++r) {
            const int m = w * 16 + rg * 4 + r;     // dd
            const int c = ni * 16 + cl;            // kd
            Cs8[m * 64 + c] = (signed char)(int)a3[ni][r];
        }
    __syncthreads();
    const size_t c8 = ((size_t)bh * 64 + n) * 4096;
    *(int4*)(CKV8 + c8 + tid * 16) = *(const int4*)(Cs8 + tid * 16);
}

// ---------------------------------------------------------------------------
// K3: integer exclusive scan of CKV8 over chunks -> PB bf16; FM fp32 exact.
// ---------------------------------------------------------------------------
__global__ __launch_bounds__(256)
void k_scan2(const signed char* __restrict__ CKV8, short* __restrict__ PB,
             float* __restrict__ FM, float* __restrict__ FC)
{
    const int bh = blockIdx.x >> 4;
    const int e  = (blockIdx.x & 15) * 256 + threadIdx.x;   // dd*64+kd
    const size_t b8 = (size_t)bh * N_ * 4096 + e;
    const size_t bp = (size_t)bh * N_ * 4096 + e;
    int run = 0;
    #pragma unroll
    for (int nn = 0; nn < 64; ++nn) {
        PB[bp + (size_t)nn * 4096] = (short)f2bf((float)run);
        run += (int)CKV8[b8 + (size_t)nn * 4096];
    }
    FM[(size_t)bh * 4096 + (e & 63) * 64 + (e >> 6)] = (float)run;
    if ((blockIdx.x & 15) == 0 && threadIdx.x == 0) FC[bh] = (float)T_;
}

// ---------------------------------------------------------------------------
// K4 (MFMA, fused): S = mask(Q K^T); intra = S V; cross = Q @ P;
// OMb = bf16((intra + cross) / total).
// ---------------------------------------------------------------------------
__global__ __launch_bounds__(256)
void k_cross3(const short* __restrict__ Qb, const signed char* __restrict__ Kb8,
              const signed char* __restrict__ VbT8, const short* __restrict__ PB,
              short* __restrict__ OMb)
{
    __shared__ __align__(16) short Qs[4096], Ks[4096], VTs[4096], Ps[4096], Ss[4096];
    const int tid = threadIdx.x;
    const int bh = blockIdx.x >> 6, n = blockIdx.x & 63;
    const size_t cbase = ((size_t)bh * T_ + n * 64) * 64;
    const size_t kbase = cbase;                                    // [c][dd]
    const size_t vbase = (size_t)bh * T_ * 64 + (size_t)n * 4096;  // [dd][c]

    auto stage_tile = [&](const short* g, short* l) {
        #pragma unroll
        for (int p = 0; p < 2; ++p) {
            const int off = tid * 16 + p * 4096;
            const int r = off >> 7;
            s16x8 v = *(const s16x8*)(g + (off >> 1));
            *(s16x8*)((char*)l + (off ^ ((r & 7) << 4))) = v;
        }
    };
    stage_tile(Qb + cbase, Qs);
    stage_tile(PB + ((size_t)bh * 64 + n) * 4096, Ps);
    {
        const int off = tid * 16;
        int4 kr = *(const int4*)(Kb8 + kbase + off);
        const signed char* kb = (const signed char*)&kr;
        int4 vr = *(const int4*)(VbT8 + vbase + off);
        const signed char* vb = (const signed char*)&vr;
        const int row = off >> 6, cb = off & 63;
        #pragma unroll
        for (int jj = 0; jj < 2; ++jj) {
            s16x8 kv, vv;
            #pragma unroll
            for (int j = 0; j < 8; ++j) {
                kv[j] = (kb[jj*8+j] >= 0) ? BF_P1 : BF_M1;
                vv[j] = (vb[jj*8+j] >= 0) ? BF_P1 : BF_M1;
            }
            const int o = (row * 128 + (cb + jj * 8) * 2) ^ ((row & 7) << 4);
            *(s16x8*)((char*)Ks  + o) = kv;
            *(s16x8*)((char*)VTs + o) = vv;
        }
    }
    __syncthreads();

    const int lane = tid & 63, w = tid >> 6;
    const int cl = lane & 15, rg = lane >> 4;
    auto frag = [&](const short* l, int rowbase, int kk) -> s16x8 {
        const int row = rowbase + cl;
        int off = row * 128 + kk * 64 + rg * 16;
        off ^= (row & 7) << 4;
        return *(const s16x8*)((const char*)l + off);
    };

    const s16x8 qa0 = frag(Qs, w * 16, 0), qa1 = frag(Qs, w * 16, 1);
    {
        f32x4 a1[4];
        #pragma unroll
        for (int ni = 0; ni < 4; ++ni) a1[ni] = (f32x4)0.f;
        #pragma unroll
        for (int ni = 0; ni < 4; ++ni) {
            a1[ni] = MFMA16(qa0, frag(Ks, ni * 16, 0), a1[ni]);
            a1[ni] = MFMA16(qa1, frag(Ks, ni * 16, 1), a1[ni]);
        }
        #pragma unroll
        for (int ni = 0; ni < 4; ++ni)
            #pragma unroll
            for (int r = 0; r < 4; ++r) {
                const int i = w * 16 + rg * 4 + r, j = ni * 16 + cl;
                const float v = (j <= i) ? a1[ni][r] : 0.f;
                const int off = (i * 128 + j * 2) ^ ((i & 7) << 4);
                *(short*)((char*)Ss + off) = (short)f2bf(v);
            }
    }
    __syncthreads();

    {
        f32x4 a2[4], a3[4];
        #pragma unroll
        for (int ni = 0; ni < 4; ++ni) { a2[ni] = (f32x4)0.f; a3[ni] = (f32x4)0.f; }
        const s16x8 sa0 = frag(Ss, w * 16, 0), sa1 = frag(Ss, w * 16, 1);
        #pragma unroll
        for (int ni = 0; ni < 4; ++ni) {
            a2[ni] = MFMA16(sa0, frag(VTs, ni * 16, 0), a2[ni]);
            a2[ni] = MFMA16(sa1, frag(VTs, ni * 16, 1), a2[ni]);
            a3[ni] = MFMA16(qa0, frag(Ps, ni * 16, 0), a3[ni]);
            a3[ni] = MFMA16(qa1, frag(Ps, ni * 16, 1), a3[ni]);
        }
        #pragma unroll
        for (int ni = 0; ni < 4; ++ni)
            #pragma unroll
            for (int r = 0; r < 4; ++r) {
                const int i = w * 16 + rg * 4 + r, j = ni * 16 + cl;
                const float invt = 1.0f / (float)(n * 64 + i + 1);
                const float f = (a2[ni][r] + a3[ni][r]) * invt;
                const int off = (i * 128 + j * 2) ^ ((i & 7) << 4);
                *(short*)((char*)Qs + off) = (short)f2bf(f);
            }
    }
    __syncthreads();

    const int bb = bh >> 4, h = bh & 15;
    #pragma unroll
    for (int p = 0; p < 2; ++p) {
        const int off = tid * 16 + p * 4096;
        const int r = off >> 7;
        const int lo = off ^ ((r & 7) << 4);
        s16x8 v = *(const s16x8*)((char*)Qs + lo);
        const size_t gi = ((size_t)bb * T_ + n * 64 + r) * D_
                        + h * 64 + ((off & 127) >> 1);
        *(s16x8*)(OMb + gi) = v;
    }
}

extern "C" void kernel_launch(void* const* d_in, const int* in_sizes, int n_in,
                              void* d_out, int out_size, void* d_ws, size_t ws_size,
                              hipStream_t stream)
{
    const float* X    = (const float*)d_in[0];
    const float* Wqkv = (const float*)d_in[1];
    const float* Wo   = (const float*)d_in[2];

    float* Y  = (float*)d_out;                       // [B,T,D]
    float* FM = Y + (size_t)B_ * T_ * D_;            // [B,H,64,64]
    float* FC = FM + (size_t)B_ * H_ * HD_ * HD_;    // [B,H,1,1]

    char* ws = (char*)d_ws;
    const size_t Mi = 1048576;
    // Timeline: cvt3 {X->Xb@96, Wqkv->Wqkvb@144, Wo->WoS@150}; fused qkv GEMM
    // (Xb,Wqkvb -> Qb@0, Kb8@32, VbT8@48); chunkA -> CKV8@128;
    // scan2 -> PB@64, FM, FC; cross3 -> OMb@96 (over dead Xb);
    // out GEMM (OMb,WoS -> Y).
    short*       Qb     = (short*)(ws + 0 * Mi);         // 32 MiB
    signed char* Kb8    = (signed char*)(ws + 32 * Mi);  // 16 MiB
    signed char* VbT8   = (signed char*)(ws + 48 * Mi);  // 16 MiB
    short*       PB     = (short*)(ws + 64 * Mi);        // 32 MiB
    short*       Xb     = (short*)(ws + 96 * Mi);        // 32 MiB (early)
    short*       OMb    = (short*)(ws + 96 * Mi);        // 32 MiB (late)
    signed char* CKV8   = (signed char*)(ws + 128 * Mi); // 16 MiB
    short*       Wqkvb  = (short*)(ws + 144 * Mi);       //  6 MiB
    short*       WoS    = (short*)(ws + 150 * Mi);       //  2 MiB
    if (ws_size < (size_t)152 * Mi) return;

    dim3 blk(256), blkg(512);
    // all three conversions in one launch
    k_cvt3<<<dim3(2048), blk, 0, stream>>>(X, Xb, 4194304,
                                           Wqkv, Wqkvb, 786432,
                                           Wo, WoS, 262144);
    // fused QKV GEMM: M=16384, N=3072, K=1024 -> NCB=24, grid 1536
    k_gemm2<0, 1024, 24><<<dim3(1536), blkg, 0, stream>>>(Xb, Wqkvb, Qb, Kb8, VbT8, nullptr);
    k_chunkA<<<dim3(4096), blk, 0, stream>>>(Kb8, VbT8, CKV8);
    k_scan2 <<<dim3(1024), blk, 0, stream>>>(CKV8, PB, FM, FC);
    k_cross3<<<dim3(4096), blk, 0, stream>>>(Qb, Kb8, VbT8, PB, OMb);
    // out GEMM: M=16384, N=1024, K=1024 -> NCB=8, grid 512
    k_gemm2<1, 1024, 8><<<dim3(512), blkg, 0, stream>>>(OMb, WoS, nullptr, nullptr, nullptr, Y);
}